// Round 8
// baseline (339.108 us; speedup 1.0000x reference)
//
#include <hip/hip_runtime.h>
#include <hip/hip_bf16.h>
#include <math.h>

// Attention_29953101922931: B=8,S=1024,H=16,D=64,W=1024
// R10: attn — LDS staging DROPPED (m169: staging L2-fit data is pure overhead;
//      R9's XCD grouping made K/V 4MB = one L2, same-CU blocks share bh).
//      K/V frags read directly from global (addresses = staging XOR composed
//      with read XOR -> identity; Vt key-perm makes V frags contiguous).
//      Kernel is now barrier-free, zero LDS.
//      qkv — epilogue vectorized: z<2 swaps MFMA operands (mfma(bfr,af)) so
//      the 4 C-frag reg values are consecutive d -> ushort4 stores + float4
//      bias; z=2 keeps order (key-perm keeps r in low bits of sp -> ushort4).
//      64 scalar stores/thread -> 16 vector stores.

#define B_ 8
#define S_ 1024
#define H_ 16
#define D_ 64
#define W_ 1024

typedef __bf16 bf16x8 __attribute__((ext_vector_type(8)));
typedef float f32x4 __attribute__((ext_vector_type(4)));
typedef unsigned short ushort_t;

#define MFMA16(a, b, c) __builtin_amdgcn_mfma_f32_16x16x32_bf16((a), (b), (c), 0, 0, 0)

__device__ inline ushort_t f2bf(float f) {  // RTNE fp32->bf16
    unsigned int u = __float_as_uint(f);
    u += 0x7fff + ((u >> 16) & 1);
    return (ushort_t)(u >> 16);
}

__device__ inline unsigned f2bf_rhu_u(float f) {  // round-half-up bf16 bits (p>=0)
    return (__float_as_uint(f) + 0x8000u) >> 16;
}

__device__ inline void async16(const void* g, void* l) {
    __builtin_amdgcn_global_load_lds((const __attribute__((address_space(1))) void*)g,
                                     (__attribute__((address_space(3))) void*)l, 16, 0, 0);
}

// Merged prep: grid (8192, 3). z=0/1: cast from/to -> bf16 (float4 lanes).
// z=2: W transposes (3072 active blocks: matrix zz = bx>>10, tile bx&1023).
__global__ __launch_bounds__(256) void prep(const float* __restrict__ from,
                                            const float* __restrict__ to_,
                                            const float* __restrict__ Wq,
                                            const float* __restrict__ Wk,
                                            const float* __restrict__ Wv,
                                            ushort_t* __restrict__ fromB,
                                            ushort_t* __restrict__ toB,
                                            ushort_t* __restrict__ Wt, int n4) {
    int z = blockIdx.y;
    int t = threadIdx.x;
    if (z < 2) {
        int i = blockIdx.x * 256 + t;
        if (i >= n4) return;
        const float* src = z ? to_ : from;
        ushort_t* dst = z ? toB : fromB;
        float4 v = ((const float4*)src)[i];
        ushort4 o;
        o.x = f2bf(v.x); o.y = f2bf(v.y); o.z = f2bf(v.z); o.w = f2bf(v.w);
        ((ushort4*)dst)[i] = o;
        return;
    }
    int bx = blockIdx.x;
    if (bx >= 3072) return;
    __shared__ float tile[32][33];
    int zz = bx >> 10;
    int tl = bx & 1023;
    int bxx = tl & 31, byy = tl >> 5;
    const float* src = (zz == 0) ? Wq : (zz == 1 ? Wk : Wv);
    ushort_t* dst = Wt + (size_t)zz * W_ * W_;
    int tx = t & 31, ty = t >> 5;  // (32,8)
    int x = bxx * 32 + tx;
#pragma unroll
    for (int jj = 0; jj < 4; jj++) {
        int y = byy * 32 + ty + jj * 8;
        tile[ty + jj * 8][tx] = src[(size_t)y * W_ + x];
    }
    __syncthreads();
    int x2 = byy * 32 + tx;
#pragma unroll
    for (int jj = 0; jj < 4; jj++) {
        int y2 = bxx * 32 + ty + jj * 8;
        dst[(size_t)y2 * W_ + x2] = f2bf(tile[tx][ty + jj * 8]);
    }
}

// C = A[M,K] x Bt[N,K]^T + bias. M=8192,N=1024,K=1024. 128x128 tile, BK=32.
// grid (512, 3): XCD remap (FETCH 170->53MB proven). m97-style 2-barrier loop.
// z<2: operands SWAPPED (mfma(bfr,af)) -> lane holds C[n=..qd*4+r][m=..ln]:
//   4 reg values = consecutive d -> ushort4 store, float4 bias.
// z=2: normal order; key-perm sp keeps r in low bits -> ushort4 store.
// z: 0=Q (scaled 0.125*log2e, [B,H,S,D]) 1=K ([B,H,S,D])
// 2=V ([B,H,D,S] with within-64 key-bit permutation for attn's in-reg PV)
__global__ __launch_bounds__(256) void qkv_gemm(const ushort_t* __restrict__ fromB,
                                                const ushort_t* __restrict__ toB,
                                                const ushort_t* __restrict__ Wt,
                                                const float* __restrict__ bq,
                                                const float* __restrict__ bk,
                                                const float* __restrict__ bv,
                                                ushort_t* __restrict__ Qd,
                                                ushort_t* __restrict__ Kd,
                                                ushort_t* __restrict__ Vt) {
    __shared__ __attribute__((aligned(16))) ushort_t As[128 * 32];
    __shared__ __attribute__((aligned(16))) ushort_t Bs[128 * 32];
    int z = blockIdx.y;
    const ushort_t* A = (z == 0) ? fromB : toB;
    const ushort_t* Bt = Wt + (size_t)z * (W_ * W_);
    const float* bias = (z == 0) ? bq : (z == 1 ? bk : bv);
    ushort_t* dst = (z == 0) ? Qd : (z == 1 ? Kd : Vt);

    // XCD-aware remap (512 blocks/z = 64 per XCD; dispatch round-robin xcd=bx&7)
    int bx = blockIdx.x;
    int j64 = bx >> 3;
    int mTile = ((bx & 7) << 3) | (j64 >> 3);  // 8 M-tiles per XCD
    int nTile = j64 & 7;                        // N fastest within XCD
    int mBase = mTile * 128, nBase = nTile * 128;

    int t = threadIdx.x;
    int lane = t & 63, w = t >> 6;
    int wm = w >> 1, wn = w & 1;
    int ln = lane & 15, qd = lane >> 4;
    int wb = t & ~63;

    f32x4 zero = {0.f, 0.f, 0.f, 0.f};
    f32x4 acc[4][4];
#pragma unroll
    for (int i = 0; i < 4; i++)
#pragma unroll
        for (int j = 0; j < 4; j++) acc[i][j] = zero;

    for (int kt = 0; kt < 32; ++kt) {
        int k0 = kt * 32;
#pragma unroll
        for (int c = 0; c < 2; ++c) {
            int idx16 = c * 256 + t;
            int row = idx16 >> 2, seg = idx16 & 3;
            async16(A + (size_t)(mBase + row) * W_ + k0 + seg * 8, As + (size_t)(c * 256 + wb) * 8);
            async16(Bt + (size_t)(nBase + row) * W_ + k0 + seg * 8, Bs + (size_t)(c * 256 + wb) * 8);
        }
        __syncthreads();
        bf16x8 af[4], bfr[4];
#pragma unroll
        for (int i = 0; i < 4; i++) af[i] = *(const bf16x8*)(As + (wm * 64 + i * 16 + ln) * 32 + qd * 8);
#pragma unroll
        for (int j = 0; j < 4; j++) bfr[j] = *(const bf16x8*)(Bs + (wn * 64 + j * 16 + ln) * 32 + qd * 8);
        if (z < 2) {
#pragma unroll
            for (int i = 0; i < 4; i++)
#pragma unroll
                for (int j = 0; j < 4; j++) acc[i][j] = MFMA16(bfr[j], af[i], acc[i][j]);
        } else {
#pragma unroll
            for (int i = 0; i < 4; i++)
#pragma unroll
                for (int j = 0; j < 4; j++) acc[i][j] = MFMA16(af[i], bfr[j], acc[i][j]);
        }
        __syncthreads();
    }

    if (z < 2) {
        // lane holds C[n = nBase+wn*64+j*16+qd*4+r][m = mBase+wm*64+i*16+ln]
        float qs = (z == 0) ? 0.18033688011111773f : 1.0f;  // (1/8)*log2(e)
#pragma unroll
        for (int j = 0; j < 4; j++) {
            int n0 = nBase + wn * 64 + j * 16 + qd * 4;
            float4 b4 = *(const float4*)&bias[n0];
            int h = n0 >> 6, d0 = n0 & 63;
#pragma unroll
            for (int i = 0; i < 4; i++) {
                int m = mBase + wm * 64 + i * 16 + ln;
                int b = m >> 10, s = m & 1023;
                ushort4 o;
                o.x = f2bf((acc[i][j][0] + b4.x) * qs);
                o.y = f2bf((acc[i][j][1] + b4.y) * qs);
                o.z = f2bf((acc[i][j][2] + b4.z) * qs);
                o.w = f2bf((acc[i][j][3] + b4.w) * qs);
                *(ushort4*)&dst[((size_t)(b * H_ + h) * S_ + s) * D_ + d0] = o;
            }
        }
    } else {
        // lane holds C[m = mBase+wm*64+i*16+qd*4+r][n = nBase+wn*64+j*16+ln];
        // key-perm: sp = (s&~63)|(s&0x23)|((s&0x0C)<<1)|((s&0x10)>>2), r-bits
        // low -> 4 reg values consecutive in sp.
#pragma unroll
        for (int j = 0; j < 4; j++) {
            int n = nBase + wn * 64 + j * 16 + ln;
            float bb = bias[n];
            int h = n >> 6, d = n & 63;
#pragma unroll
            for (int i = 0; i < 4; i++) {
                int s0 = mBase + wm * 64 + i * 16 + qd * 4;  // r=0; s0%4==0
                int b = s0 >> 10, s = s0 & 1023;
                int sp0 = (s & ~63) | (s & 0x23) | ((s & 0x0C) << 1) | ((s & 0x10) >> 2);
                ushort4 o;
                o.x = f2bf(acc[i][j][0] + bb);
                o.y = f2bf(acc[i][j][1] + bb);
                o.z = f2bf(acc[i][j][2] + bb);
                o.w = f2bf(acc[i][j][3] + bb);
                *(ushort4*)&dst[((size_t)(b * H_ + h) * D_ + d) * S_ + sp0] = o;
            }
        }
    }
}

// Flash attention, barrier-free, zero LDS. grid 1024 linear, block 256
// (4 waves x 32 queries), 4 blk/CU. XCD grouping: bh=((L&7)<<4)|((L>>3)&15),
// qx=L>>7 -> XCD c owns bh [16c,16c+16) (K/V 4MB = one L2; same-CU blocks
// share bh -> L1 reuse). K/V frags loaded DIRECTLY from global (L2-hit):
//   K: Kb[(c*64+j*16+ln)*64 + qd*8] (+32 for k1) — staging XOR composed with
//      read XOR is identity, so direct addressing is equivalent.
//   V: Vb[(dt*16+ln)*S + c*64 + m*32 + qd*8] — Vt key-perm makes the frag's
//      keys contiguous; element e <-> key 32m+16(e>>2)+4qd+(e&3) = pfrag map.
// Swapped QK^T: sc[i][j][r] = P[key=j*16+qd*4+r][q=i*16+ln]; softmax+P->bf16
// in-register (pfrag = PV B-operand). O^T epilogue: contiguous float4 stores.
__global__ __launch_bounds__(256, 4) void attn(const ushort_t* __restrict__ Qd,
                                               const ushort_t* __restrict__ Kd,
                                               const ushort_t* __restrict__ Vt,
                                               float* __restrict__ out) {
    int L = blockIdx.x;
    int bh = ((L & 7) << 4) | ((L >> 3) & 15);
    int qx = L >> 7;
    int t = threadIdx.x, w = t >> 6, lane = t & 63;
    int ln = lane & 15, qd = lane >> 4;
    int qbase = qx * 128 + w * 32;
    const ushort_t* Qb = Qd + (size_t)bh * S_ * D_;
    const ushort_t* Kb = Kd + (size_t)bh * S_ * D_;
    const ushort_t* Vb = Vt + (size_t)bh * D_ * S_;

    // Q frags: lane ln holds row (q), qd*8 d-offset (B operand of swapped QK^T)
    bf16x8 qf[2][2];
#pragma unroll
    for (int i = 0; i < 2; i++) {
        const ushort_t* qp = Qb + (size_t)(qbase + i * 16 + ln) * D_ + qd * 8;
        qf[i][0] = *(const bf16x8*)qp;
        qf[i][1] = *(const bf16x8*)(qp + 32);
    }

    // per-lane constant bases for direct K/V frag loads
    const ushort_t* kp = Kb + (size_t)ln * D_ + qd * 8;          // + (c*64+j*16)*64
    const ushort_t* vp0 = Vb + (size_t)ln * S_ + qd * 8;         // + dt*16*S + c*64 + m*32

    float rs[2] = {0.f, 0.f};
    f32x4 zero = {0.f, 0.f, 0.f, 0.f};
    f32x4 accO[2][4];
#pragma unroll
    for (int i = 0; i < 2; i++)
#pragma unroll
        for (int jd = 0; jd < 4; jd++) accO[i][jd] = zero;

    for (int c = 0; c < 16; ++c) {
        // S^T = K Q^T (swapped): sc[i][j][r] = P[key=j*16+qd*4+r][q=i*16+ln]
        f32x4 sc[2][4];
#pragma unroll
        for (int i = 0; i < 2; i++)
#pragma unroll
            for (int j = 0; j < 4; j++) sc[i][j] = zero;
        __builtin_amdgcn_s_setprio(1);
#pragma unroll
        for (int j = 0; j < 4; j++) {
            const ushort_t* kr = kp + (size_t)(c * 64 + j * 16) * D_;
            bf16x8 k0 = *(const bf16x8*)kr;
            bf16x8 k1 = *(const bf16x8*)(kr + 32);
#pragma unroll
            for (int i = 0; i < 2; i++) {
                sc[i][j] = MFMA16(k0, qf[i][0], sc[i][j]);
                sc[i][j] = MFMA16(k1, qf[i][1], sc[i][j]);
            }
        }
        __builtin_amdgcn_s_setprio(0);

        // softmax + P^T B-frags in-register: pfrag[i][m] element e holds
        // bf16(exp2(sc[i][2m+(e>>2)][e&3])) = P[key 32m+16jh+4qd+r][q]
        bf16x8 pfrag[2][2];
#pragma unroll
        for (int i = 0; i < 2; i++)
#pragma unroll
            for (int m = 0; m < 2; m++) {
                union { unsigned u[4]; bf16x8 v; } pk;
#pragma unroll
                for (int jh = 0; jh < 2; jh++) {
                    float p0 = exp2f(sc[i][2 * m + jh][0]);
                    float p1 = exp2f(sc[i][2 * m + jh][1]);
                    float p2 = exp2f(sc[i][2 * m + jh][2]);
                    float p3 = exp2f(sc[i][2 * m + jh][3]);
                    rs[i] += (p0 + p1) + (p2 + p3);
                    pk.u[jh * 2]     = f2bf_rhu_u(p0) | (f2bf_rhu_u(p1) << 16);
                    pk.u[jh * 2 + 1] = f2bf_rhu_u(p2) | (f2bf_rhu_u(p3) << 16);
                }
                pfrag[i][m] = pk.v;
            }

        // O^T += V^T P^T (V A-frags direct from L2, perm-keys contiguous)
        __builtin_amdgcn_s_setprio(1);
#pragma unroll
        for (int dt = 0; dt < 4; dt++)
#pragma unroll
            for (int m = 0; m < 2; m++) {
                bf16x8 vf = *(const bf16x8*)(vp0 + (size_t)dt * 16 * S_ + c * 64 + m * 32);
                accO[0][dt] = MFMA16(vf, pfrag[0][m], accO[0][dt]);
                accO[1][dt] = MFMA16(vf, pfrag[1][m], accO[1][dt]);
            }
        __builtin_amdgcn_s_setprio(0);
    }

    // denominators: rs[i] = this lane's partial for q=i*16+ln (16 keys/chunk);
    // full sum over the 4 qd lanes (xor bits 4,5). inv valid on every lane.
    float inv[2];
#pragma unroll
    for (int i = 0; i < 2; i++) {
        float s = rs[i];
        s += __shfl_xor(s, 16);
        s += __shfl_xor(s, 32);
        inv[i] = 1.f / s;
    }
    int b = bh >> 4, h = bh & 15;
#pragma unroll
    for (int i = 0; i < 2; i++) {
        int q = qbase + i * 16 + ln;
        float* op = out + ((size_t)(b * S_ + q) * H_ + h) * D_ + qd * 4;
#pragma unroll
        for (int dt = 0; dt < 4; dt++) {
            float4 o4;
            o4.x = accO[i][dt][0] * inv[i];
            o4.y = accO[i][dt][1] * inv[i];
            o4.z = accO[i][dt][2] * inv[i];
            o4.w = accO[i][dt][3] * inv[i];
            *(float4*)(op + dt * 16) = o4;
        }
    }
}

extern "C" void kernel_launch(void* const* d_in, const int* in_sizes, int n_in,
                              void* d_out, int out_size, void* d_ws, size_t ws_size,
                              hipStream_t stream) {
    const float* from = (const float*)d_in[0];
    const float* to_  = (const float*)d_in[1];
    const float* Wq = (const float*)d_in[2];
    const float* bq = (const float*)d_in[3];
    const float* Wk = (const float*)d_in[4];
    const float* bk = (const float*)d_in[5];
    const float* Wv = (const float*)d_in[6];
    const float* bv = (const float*)d_in[7];
    float* out = (float*)d_out;

    const size_t NTOK = (size_t)B_ * S_ * W_;  // 8388608
    ushort_t* ws = (ushort_t*)d_ws;
    ushort_t* fromB = ws;
    ushort_t* toB = fromB + NTOK;
    ushort_t* Wt = toB + NTOK;
    ushort_t* Qd = Wt + (size_t)3 * W_ * W_;
    ushort_t* Kd = Qd + NTOK;
    ushort_t* Vt = Kd + NTOK;

    int n4 = (int)(NTOK / 4);
    prep<<<dim3(n4 / 256, 3), dim3(256), 0, stream>>>(from, to_, Wq, Wk, Wv, fromB, toB, Wt, n4);
    qkv_gemm<<<dim3(512, 3), dim3(256), 0, stream>>>(fromB, toB, Wt, bq, bk, bv, Qd, Kd, Vt);
    attn<<<dim3(1024), dim3(256), 0, stream>>>(Qd, Kd, Vt, out);
}

// Round 9
// 258.852 us; speedup vs baseline: 1.3100x; 1.3100x over previous
//
#include <hip/hip_runtime.h>
#include <hip/hip_bf16.h>
#include <math.h>

// Attention_29953101922931: B=8,S=1024,H=16,D=64,W=1024
// R11: attn RESTORED to R9-exact (LDS-staged, double-buffered, prefetch 1
//      chunk ahead — R10's direct-L2 reads were latency-bound: MfmaUtil 9%,
//      ~200cyc L2-hit latency on the MFMA critical path with no prefetch).
//      prep/qkv kept from R10 (passed; vectorized epilogue ~neutral, fewer
//      instructions). Proven stack: qkv XCD remap (FETCH 170->53MB), attn XCD
//      bh-grouping (K/V 4MB = one L2), swapped QK^T + in-reg softmax/PV with
//      key-permuted Vt, 4 blocks/CU.

#define B_ 8
#define S_ 1024
#define H_ 16
#define D_ 64
#define W_ 1024

typedef __bf16 bf16x8 __attribute__((ext_vector_type(8)));
typedef float f32x4 __attribute__((ext_vector_type(4)));
typedef unsigned short ushort_t;

#define MFMA16(a, b, c) __builtin_amdgcn_mfma_f32_16x16x32_bf16((a), (b), (c), 0, 0, 0)

__device__ inline ushort_t f2bf(float f) {  // RTNE fp32->bf16
    unsigned int u = __float_as_uint(f);
    u += 0x7fff + ((u >> 16) & 1);
    return (ushort_t)(u >> 16);
}

__device__ inline unsigned f2bf_rhu_u(float f) {  // round-half-up bf16 bits (p>=0)
    return (__float_as_uint(f) + 0x8000u) >> 16;
}

__device__ inline void async16(const void* g, void* l) {
    __builtin_amdgcn_global_load_lds((const __attribute__((address_space(1))) void*)g,
                                     (__attribute__((address_space(3))) void*)l, 16, 0, 0);
}

// Merged prep: grid (8192, 3). z=0/1: cast from/to -> bf16 (float4 lanes).
// z=2: W transposes (3072 active blocks: matrix zz = bx>>10, tile bx&1023).
__global__ __launch_bounds__(256) void prep(const float* __restrict__ from,
                                            const float* __restrict__ to_,
                                            const float* __restrict__ Wq,
                                            const float* __restrict__ Wk,
                                            const float* __restrict__ Wv,
                                            ushort_t* __restrict__ fromB,
                                            ushort_t* __restrict__ toB,
                                            ushort_t* __restrict__ Wt, int n4) {
    int z = blockIdx.y;
    int t = threadIdx.x;
    if (z < 2) {
        int i = blockIdx.x * 256 + t;
        if (i >= n4) return;
        const float* src = z ? to_ : from;
        ushort_t* dst = z ? toB : fromB;
        float4 v = ((const float4*)src)[i];
        ushort4 o;
        o.x = f2bf(v.x); o.y = f2bf(v.y); o.z = f2bf(v.z); o.w = f2bf(v.w);
        ((ushort4*)dst)[i] = o;
        return;
    }
    int bx = blockIdx.x;
    if (bx >= 3072) return;
    __shared__ float tile[32][33];
    int zz = bx >> 10;
    int tl = bx & 1023;
    int bxx = tl & 31, byy = tl >> 5;
    const float* src = (zz == 0) ? Wq : (zz == 1 ? Wk : Wv);
    ushort_t* dst = Wt + (size_t)zz * W_ * W_;
    int tx = t & 31, ty = t >> 5;  // (32,8)
    int x = bxx * 32 + tx;
#pragma unroll
    for (int jj = 0; jj < 4; jj++) {
        int y = byy * 32 + ty + jj * 8;
        tile[ty + jj * 8][tx] = src[(size_t)y * W_ + x];
    }
    __syncthreads();
    int x2 = byy * 32 + tx;
#pragma unroll
    for (int jj = 0; jj < 4; jj++) {
        int y2 = bxx * 32 + ty + jj * 8;
        dst[(size_t)y2 * W_ + x2] = f2bf(tile[tx][ty + jj * 8]);
    }
}

// C = A[M,K] x Bt[N,K]^T + bias. M=8192,N=1024,K=1024. 128x128 tile, BK=32.
// grid (512, 3): XCD remap (FETCH 170->53MB proven). m97-style 2-barrier loop.
// z<2: operands SWAPPED (mfma(bfr,af)) -> lane holds C[n=..qd*4+r][m=..ln]:
//   4 reg values = consecutive d -> ushort4 store, float4 bias.
// z=2: normal order; key-perm sp keeps r in low bits -> ushort4 store.
// z: 0=Q (scaled 0.125*log2e, [B,H,S,D]) 1=K ([B,H,S,D])
// 2=V ([B,H,D,S] with within-64 key-bit permutation for attn's in-reg PV)
__global__ __launch_bounds__(256) void qkv_gemm(const ushort_t* __restrict__ fromB,
                                                const ushort_t* __restrict__ toB,
                                                const ushort_t* __restrict__ Wt,
                                                const float* __restrict__ bq,
                                                const float* __restrict__ bk,
                                                const float* __restrict__ bv,
                                                ushort_t* __restrict__ Qd,
                                                ushort_t* __restrict__ Kd,
                                                ushort_t* __restrict__ Vt) {
    __shared__ __attribute__((aligned(16))) ushort_t As[128 * 32];
    __shared__ __attribute__((aligned(16))) ushort_t Bs[128 * 32];
    int z = blockIdx.y;
    const ushort_t* A = (z == 0) ? fromB : toB;
    const ushort_t* Bt = Wt + (size_t)z * (W_ * W_);
    const float* bias = (z == 0) ? bq : (z == 1 ? bk : bv);
    ushort_t* dst = (z == 0) ? Qd : (z == 1 ? Kd : Vt);

    // XCD-aware remap (512 blocks/z = 64 per XCD; dispatch round-robin xcd=bx&7)
    int bx = blockIdx.x;
    int j64 = bx >> 3;
    int mTile = ((bx & 7) << 3) | (j64 >> 3);  // 8 M-tiles per XCD
    int nTile = j64 & 7;                        // N fastest within XCD
    int mBase = mTile * 128, nBase = nTile * 128;

    int t = threadIdx.x;
    int lane = t & 63, w = t >> 6;
    int wm = w >> 1, wn = w & 1;
    int ln = lane & 15, qd = lane >> 4;
    int wb = t & ~63;

    f32x4 zero = {0.f, 0.f, 0.f, 0.f};
    f32x4 acc[4][4];
#pragma unroll
    for (int i = 0; i < 4; i++)
#pragma unroll
        for (int j = 0; j < 4; j++) acc[i][j] = zero;

    for (int kt = 0; kt < 32; ++kt) {
        int k0 = kt * 32;
#pragma unroll
        for (int c = 0; c < 2; ++c) {
            int idx16 = c * 256 + t;
            int row = idx16 >> 2, seg = idx16 & 3;
            async16(A + (size_t)(mBase + row) * W_ + k0 + seg * 8, As + (size_t)(c * 256 + wb) * 8);
            async16(Bt + (size_t)(nBase + row) * W_ + k0 + seg * 8, Bs + (size_t)(c * 256 + wb) * 8);
        }
        __syncthreads();
        bf16x8 af[4], bfr[4];
#pragma unroll
        for (int i = 0; i < 4; i++) af[i] = *(const bf16x8*)(As + (wm * 64 + i * 16 + ln) * 32 + qd * 8);
#pragma unroll
        for (int j = 0; j < 4; j++) bfr[j] = *(const bf16x8*)(Bs + (wn * 64 + j * 16 + ln) * 32 + qd * 8);
        if (z < 2) {
#pragma unroll
            for (int i = 0; i < 4; i++)
#pragma unroll
                for (int j = 0; j < 4; j++) acc[i][j] = MFMA16(bfr[j], af[i], acc[i][j]);
        } else {
#pragma unroll
            for (int i = 0; i < 4; i++)
#pragma unroll
                for (int j = 0; j < 4; j++) acc[i][j] = MFMA16(af[i], bfr[j], acc[i][j]);
        }
        __syncthreads();
    }

    if (z < 2) {
        // lane holds C[n = nBase+wn*64+j*16+qd*4+r][m = mBase+wm*64+i*16+ln]
        float qs = (z == 0) ? 0.18033688011111773f : 1.0f;  // (1/8)*log2(e)
#pragma unroll
        for (int j = 0; j < 4; j++) {
            int n0 = nBase + wn * 64 + j * 16 + qd * 4;
            float4 b4 = *(const float4*)&bias[n0];
            int h = n0 >> 6, d0 = n0 & 63;
#pragma unroll
            for (int i = 0; i < 4; i++) {
                int m = mBase + wm * 64 + i * 16 + ln;
                int b = m >> 10, s = m & 1023;
                ushort4 o;
                o.x = f2bf((acc[i][j][0] + b4.x) * qs);
                o.y = f2bf((acc[i][j][1] + b4.y) * qs);
                o.z = f2bf((acc[i][j][2] + b4.z) * qs);
                o.w = f2bf((acc[i][j][3] + b4.w) * qs);
                *(ushort4*)&dst[((size_t)(b * H_ + h) * S_ + s) * D_ + d0] = o;
            }
        }
    } else {
        // lane holds C[m = mBase+wm*64+i*16+qd*4+r][n = nBase+wn*64+j*16+ln];
        // key-perm: sp = (s&~63)|(s&0x23)|((s&0x0C)<<1)|((s&0x10)>>2), r-bits
        // low -> 4 reg values consecutive in sp.
#pragma unroll
        for (int j = 0; j < 4; j++) {
            int n = nBase + wn * 64 + j * 16 + ln;
            float bb = bias[n];
            int h = n >> 6, d = n & 63;
#pragma unroll
            for (int i = 0; i < 4; i++) {
                int s0 = mBase + wm * 64 + i * 16 + qd * 4;  // r=0; s0%4==0
                int b = s0 >> 10, s = s0 & 1023;
                int sp0 = (s & ~63) | (s & 0x23) | ((s & 0x0C) << 1) | ((s & 0x10) >> 2);
                ushort4 o;
                o.x = f2bf(acc[i][j][0] + bb);
                o.y = f2bf(acc[i][j][1] + bb);
                o.z = f2bf(acc[i][j][2] + bb);
                o.w = f2bf(acc[i][j][3] + bb);
                *(ushort4*)&dst[((size_t)(b * H_ + h) * D_ + d) * S_ + sp0] = o;
            }
        }
    }
}

// Flash attention (R9-exact). grid 1024 linear, block 256 (4 waves x 32
// queries), 4 blk/CU. XCD grouping: bh=((L&7)<<4)|((L>>3)&15), qx=L>>7 ->
// XCD c owns bh [16c,16c+16) (K/V 4MB = one L2).
// Q,K: [B,H,S,D] bf16 (Q pre-scaled by 0.125*log2e); V: [B,H,D,S] key-permuted.
// Swapped QK^T: sc[i][j][r] = P[key=j*16+qd*4+r][q=i*16+ln]; softmax+P->bf16
// in-register (pfrag = PV B-operand); V A-frags b128 from Vs (pre-permuted Vt).
__global__ __launch_bounds__(256, 4) void attn(const ushort_t* __restrict__ Qd,
                                               const ushort_t* __restrict__ Kd,
                                               const ushort_t* __restrict__ Vt,
                                               float* __restrict__ out) {
    __shared__ __attribute__((aligned(16))) ushort_t Ks[2][4096];   // [buf][64 keys x 64 d]
    __shared__ __attribute__((aligned(16))) ushort_t Vs[2][4096];   // [buf][64 d x 64 perm-keys]

    int L = blockIdx.x;
    int bh = ((L & 7) << 4) | ((L >> 3) & 15);
    int qx = L >> 7;
    int t = threadIdx.x, w = t >> 6, lane = t & 63;
    int ln = lane & 15, qd = lane >> 4;
    int qbase = qx * 128 + w * 32;
    const ushort_t* Qb = Qd + (size_t)bh * S_ * D_;
    const ushort_t* Kb = Kd + (size_t)bh * S_ * D_;
    const ushort_t* Vb = Vt + (size_t)bh * D_ * S_;

    // Q frags: lane ln holds row (q), qd*8 d-offset (B operand of swapped QK^T)
    bf16x8 qf[2][2];
#pragma unroll
    for (int i = 0; i < 2; i++) {
        const ushort_t* qp = Qb + (size_t)(qbase + i * 16 + ln) * D_ + qd * 8;
        qf[i][0] = *(const bf16x8*)qp;
        qf[i][1] = *(const bf16x8*)(qp + 32);
    }

    // staging per-lane constants (8 rows x 64 elem per 1KB async16 block)
    int l8 = lane >> 3, s8 = lane & 7;
    int stgOff = (s8 ^ l8) << 3;  // swizzled 8-elem segment
    const ushort_t* kg = Kb + (size_t)(w * 16 + l8) * D_ + stgOff;
    const ushort_t* vg = Vb + (size_t)(w * 16 + l8) * S_ + stgOff;
    // K frag-read: row ln (mod 16), seg qd swizzled by row&7
    int kOff = ln * 64 + ((qd ^ (ln & 7)) << 3);

    float rs[2] = {0.f, 0.f};
    f32x4 zero = {0.f, 0.f, 0.f, 0.f};
    f32x4 accO[2][4];
#pragma unroll
    for (int i = 0; i < 2; i++)
#pragma unroll
        for (int jd = 0; jd < 4; jd++) accO[i][jd] = zero;

    // preload chunk 0 into buf 0 (4 async16 per wave: 2 K-blocks + 2 V-blocks)
    async16(kg, &Ks[0][w * 1024]);
    async16(kg + 8 * D_, &Ks[0][w * 1024 + 512]);
    async16(vg, &Vs[0][w * 1024]);
    async16(vg + 8 * S_, &Vs[0][w * 1024 + 512]);

    for (int c = 0; c < 16; ++c) {
        int buf = c & 1;
        __builtin_amdgcn_s_waitcnt(0x0F70);  // vmcnt(0): chunk c staged
        __syncthreads();                     // all waves: staged + done reading buf^1
        if (c + 1 < 16) {                    // prefetch c+1; lands during compute(c)
            int kc = (c + 1) * 64;
            async16(kg + (size_t)kc * D_, &Ks[buf ^ 1][w * 1024]);
            async16(kg + (size_t)kc * D_ + 8 * D_, &Ks[buf ^ 1][w * 1024 + 512]);
            async16(vg + kc, &Vs[buf ^ 1][w * 1024]);
            async16(vg + kc + 8 * S_, &Vs[buf ^ 1][w * 1024 + 512]);
        }

        // S^T = K Q^T (swapped): sc[i][j][r] = P[key=j*16+qd*4+r][q=i*16+ln]
        f32x4 sc[2][4];
#pragma unroll
        for (int i = 0; i < 2; i++)
#pragma unroll
            for (int j = 0; j < 4; j++) sc[i][j] = zero;
        __builtin_amdgcn_s_setprio(1);
#pragma unroll
        for (int j = 0; j < 4; j++) {
            bf16x8 k0 = *(const bf16x8*)&Ks[buf][j * 1024 + kOff];
            bf16x8 k1 = *(const bf16x8*)&Ks[buf][(j * 1024 + kOff) ^ 32];
#pragma unroll
            for (int i = 0; i < 2; i++) {
                sc[i][j] = MFMA16(k0, qf[i][0], sc[i][j]);
                sc[i][j] = MFMA16(k1, qf[i][1], sc[i][j]);
            }
        }
        __builtin_amdgcn_s_setprio(0);

        // softmax + P^T B-frags in-register: pfrag[i][m] element e holds
        // bf16(exp2(sc[i][2m+(e>>2)][e&3])) = P[key 32m+16jh+4qd+r][q]
        bf16x8 pfrag[2][2];
#pragma unroll
        for (int i = 0; i < 2; i++)
#pragma unroll
            for (int m = 0; m < 2; m++) {
                union { unsigned u[4]; bf16x8 v; } pk;
#pragma unroll
                for (int jh = 0; jh < 2; jh++) {
                    float p0 = exp2f(sc[i][2 * m + jh][0]);
                    float p1 = exp2f(sc[i][2 * m + jh][1]);
                    float p2 = exp2f(sc[i][2 * m + jh][2]);
                    float p3 = exp2f(sc[i][2 * m + jh][3]);
                    rs[i] += (p0 + p1) + (p2 + p3);
                    pk.u[jh * 2]     = f2bf_rhu_u(p0) | (f2bf_rhu_u(p1) << 16);
                    pk.u[jh * 2 + 1] = f2bf_rhu_u(p2) | (f2bf_rhu_u(p3) << 16);
                }
                pfrag[i][m] = pk.v;
            }

        // O^T += V^T P^T (V A-frags: row d=dt*16+ln, perm-key seg (4m+qd)^(d&7))
        __builtin_amdgcn_s_setprio(1);
#pragma unroll
        for (int dt = 0; dt < 4; dt++)
#pragma unroll
            for (int m = 0; m < 2; m++) {
                bf16x8 vf = *(const bf16x8*)&Vs[buf][(dt * 16 + ln) * 64 +
                                                    ((((m << 2) + qd) ^ (ln & 7)) << 3)];
                accO[0][dt] = MFMA16(vf, pfrag[0][m], accO[0][dt]);
                accO[1][dt] = MFMA16(vf, pfrag[1][m], accO[1][dt]);
            }
        __builtin_amdgcn_s_setprio(0);
    }

    // denominators: rs[i] = this lane's partial for q=i*16+ln (16 keys/chunk);
    // full sum over the 4 qd lanes (xor bits 4,5). inv valid on every lane.
    float inv[2];
#pragma unroll
    for (int i = 0; i < 2; i++) {
        float s = rs[i];
        s += __shfl_xor(s, 16);
        s += __shfl_xor(s, 32);
        inv[i] = 1.f / s;
    }
    int b = bh >> 4, h = bh & 15;
#pragma unroll
    for (int i = 0; i < 2; i++) {
        int q = qbase + i * 16 + ln;
        float* op = out + ((size_t)(b * S_ + q) * H_ + h) * D_ + qd * 4;
#pragma unroll
        for (int dt = 0; dt < 4; dt++) {
            float4 o4;
            o4.x = accO[i][dt][0] * inv[i];
            o4.y = accO[i][dt][1] * inv[i];
            o4.z = accO[i][dt][2] * inv[i];
            o4.w = accO[i][dt][3] * inv[i];
            *(float4*)(op + dt * 16) = o4;
        }
    }
}

extern "C" void kernel_launch(void* const* d_in, const int* in_sizes, int n_in,
                              void* d_out, int out_size, void* d_ws, size_t ws_size,
                              hipStream_t stream) {
    const float* from = (const float*)d_in[0];
    const float* to_  = (const float*)d_in[1];
    const float* Wq = (const float*)d_in[2];
    const float* bq = (const float*)d_in[3];
    const float* Wk = (const float*)d_in[4];
    const float* bk = (const float*)d_in[5];
    const float* Wv = (const float*)d_in[6];
    const float* bv = (const float*)d_in[7];
    float* out = (float*)d_out;

    const size_t NTOK = (size_t)B_ * S_ * W_;  // 8388608
    ushort_t* ws = (ushort_t*)d_ws;
    ushort_t* fromB = ws;
    ushort_t* toB = fromB + NTOK;
    ushort_t* Wt = toB + NTOK;
    ushort_t* Qd = Wt + (size_t)3 * W_ * W_;
    ushort_t* Kd = Qd + NTOK;
    ushort_t* Vt = Kd + NTOK;

    int n4 = (int)(NTOK / 4);
    prep<<<dim3(n4 / 256, 3), dim3(256), 0, stream>>>(from, to_, Wq, Wk, Wv, fromB, toB, Wt, n4);
    qkv_gemm<<<dim3(512, 3), dim3(256), 0, stream>>>(fromB, toB, Wt, bq, bk, bv, Qd, Kd, Vt);
    attn<<<dim3(1024), dim3(256), 0, stream>>>(Qd, Kd, Vt, out);
}

// Round 10
// 252.385 us; speedup vs baseline: 1.3436x; 1.0256x over previous
//
#include <hip/hip_runtime.h>
#include <hip/hip_bf16.h>
#include <math.h>

// Attention_29953101922931: B=8,S=1024,H=16,D=64,W=1024
// R12: qkv BK=64 via TWO independent 32-K LDS planes (As[2]/Bs[2], each plane
//      byte-identical layout to R11's proven [128][32]) -> one barrier-drain
//      per 64-K tile instead of two. No source permutation (R5/R7 regression),
//      no row-stride change (would 16-way-conflict). LDS 16->32KB keeps
//      residency (LDS cap 5 blk/CU > VGPR cap 4). attn/prep R11-identical.

#define B_ 8
#define S_ 1024
#define H_ 16
#define D_ 64
#define W_ 1024

typedef __bf16 bf16x8 __attribute__((ext_vector_type(8)));
typedef float f32x4 __attribute__((ext_vector_type(4)));
typedef unsigned short ushort_t;

#define MFMA16(a, b, c) __builtin_amdgcn_mfma_f32_16x16x32_bf16((a), (b), (c), 0, 0, 0)

__device__ inline ushort_t f2bf(float f) {  // RTNE fp32->bf16
    unsigned int u = __float_as_uint(f);
    u += 0x7fff + ((u >> 16) & 1);
    return (ushort_t)(u >> 16);
}

__device__ inline unsigned f2bf_rhu_u(float f) {  // round-half-up bf16 bits (p>=0)
    return (__float_as_uint(f) + 0x8000u) >> 16;
}

__device__ inline void async16(const void* g, void* l) {
    __builtin_amdgcn_global_load_lds((const __attribute__((address_space(1))) void*)g,
                                     (__attribute__((address_space(3))) void*)l, 16, 0, 0);
}

// Merged prep: grid (8192, 3). z=0/1: cast from/to -> bf16 (float4 lanes).
// z=2: W transposes (3072 active blocks: matrix zz = bx>>10, tile bx&1023).
__global__ __launch_bounds__(256) void prep(const float* __restrict__ from,
                                            const float* __restrict__ to_,
                                            const float* __restrict__ Wq,
                                            const float* __restrict__ Wk,
                                            const float* __restrict__ Wv,
                                            ushort_t* __restrict__ fromB,
                                            ushort_t* __restrict__ toB,
                                            ushort_t* __restrict__ Wt, int n4) {
    int z = blockIdx.y;
    int t = threadIdx.x;
    if (z < 2) {
        int i = blockIdx.x * 256 + t;
        if (i >= n4) return;
        const float* src = z ? to_ : from;
        ushort_t* dst = z ? toB : fromB;
        float4 v = ((const float4*)src)[i];
        ushort4 o;
        o.x = f2bf(v.x); o.y = f2bf(v.y); o.z = f2bf(v.z); o.w = f2bf(v.w);
        ((ushort4*)dst)[i] = o;
        return;
    }
    int bx = blockIdx.x;
    if (bx >= 3072) return;
    __shared__ float tile[32][33];
    int zz = bx >> 10;
    int tl = bx & 1023;
    int bxx = tl & 31, byy = tl >> 5;
    const float* src = (zz == 0) ? Wq : (zz == 1 ? Wk : Wv);
    ushort_t* dst = Wt + (size_t)zz * W_ * W_;
    int tx = t & 31, ty = t >> 5;  // (32,8)
    int x = bxx * 32 + tx;
#pragma unroll
    for (int jj = 0; jj < 4; jj++) {
        int y = byy * 32 + ty + jj * 8;
        tile[ty + jj * 8][tx] = src[(size_t)y * W_ + x];
    }
    __syncthreads();
    int x2 = byy * 32 + tx;
#pragma unroll
    for (int jj = 0; jj < 4; jj++) {
        int y2 = bxx * 32 + ty + jj * 8;
        dst[(size_t)y2 * W_ + x2] = f2bf(tile[tx][ty + jj * 8]);
    }
}

// C = A[M,K] x Bt[N,K]^T + bias. M=8192,N=1024,K=1024. 128x128 tile, BK=64
// (two 32-K planes, one barrier pair per tile). grid (512, 3): XCD remap
// (FETCH 170->53MB proven). z<2: operands SWAPPED (mfma(bfr,af)) -> lane holds
// C[n=..qd*4+r][m=..ln]: 4 reg values = consecutive d -> ushort4 stores.
// z=2: normal order; key-perm sp keeps r in low bits -> ushort4 store.
// z: 0=Q (scaled 0.125*log2e, [B,H,S,D]) 1=K ([B,H,S,D])
// 2=V ([B,H,D,S] with within-64 key-bit permutation for attn's in-reg PV)
__global__ __launch_bounds__(256) void qkv_gemm(const ushort_t* __restrict__ fromB,
                                                const ushort_t* __restrict__ toB,
                                                const ushort_t* __restrict__ Wt,
                                                const float* __restrict__ bq,
                                                const float* __restrict__ bk,
                                                const float* __restrict__ bv,
                                                ushort_t* __restrict__ Qd,
                                                ushort_t* __restrict__ Kd,
                                                ushort_t* __restrict__ Vt) {
    __shared__ __attribute__((aligned(16))) ushort_t As[2][128 * 32];
    __shared__ __attribute__((aligned(16))) ushort_t Bs[2][128 * 32];
    int z = blockIdx.y;
    const ushort_t* A = (z == 0) ? fromB : toB;
    const ushort_t* Bt = Wt + (size_t)z * (W_ * W_);
    const float* bias = (z == 0) ? bq : (z == 1 ? bk : bv);
    ushort_t* dst = (z == 0) ? Qd : (z == 1 ? Kd : Vt);

    // XCD-aware remap (512 blocks/z = 64 per XCD; dispatch round-robin xcd=bx&7)
    int bx = blockIdx.x;
    int j64 = bx >> 3;
    int mTile = ((bx & 7) << 3) | (j64 >> 3);  // 8 M-tiles per XCD
    int nTile = j64 & 7;                        // N fastest within XCD
    int mBase = mTile * 128, nBase = nTile * 128;

    int t = threadIdx.x;
    int lane = t & 63, w = t >> 6;
    int wm = w >> 1, wn = w & 1;
    int ln = lane & 15, qd = lane >> 4;
    int wb = t & ~63;

    // staging per-lane constants (plane-invariant): slot idx16 = c*256+t
    int row0 = t >> 2, seg0 = (t & 3) << 3;          // c=0
    int row1 = (256 + t) >> 2, seg1 = ((256 + t) & 3) << 3;  // c=1
    const ushort_t* a0 = A + (size_t)(mBase + row0) * W_ + seg0;
    const ushort_t* a1 = A + (size_t)(mBase + row1) * W_ + seg1;
    const ushort_t* b0 = Bt + (size_t)(nBase + row0) * W_ + seg0;
    const ushort_t* b1 = Bt + (size_t)(nBase + row1) * W_ + seg1;
    int d0 = wb * 8, d1 = (256 + wb) * 8;            // wave-uniform LDS elem offs

    f32x4 zero = {0.f, 0.f, 0.f, 0.f};
    f32x4 acc[4][4];
#pragma unroll
    for (int i = 0; i < 4; i++)
#pragma unroll
        for (int j = 0; j < 4; j++) acc[i][j] = zero;

    for (int kt = 0; kt < 16; ++kt) {
        int k0 = kt * 64;
#pragma unroll
        for (int p = 0; p < 2; ++p) {   // two 32-K planes
            int kp = k0 + p * 32;
            async16(a0 + kp, As[p] + d0);
            async16(b0 + kp, Bs[p] + d0);
            async16(a1 + kp, As[p] + d1);
            async16(b1 + kp, Bs[p] + d1);
        }
        __syncthreads();   // single drain per 64-K tile
#pragma unroll
        for (int p = 0; p < 2; ++p) {
            bf16x8 af[4], bfr[4];
#pragma unroll
            for (int i = 0; i < 4; i++) af[i] = *(const bf16x8*)(As[p] + (wm * 64 + i * 16 + ln) * 32 + qd * 8);
#pragma unroll
            for (int j = 0; j < 4; j++) bfr[j] = *(const bf16x8*)(Bs[p] + (wn * 64 + j * 16 + ln) * 32 + qd * 8);
            if (z < 2) {
#pragma unroll
                for (int i = 0; i < 4; i++)
#pragma unroll
                    for (int j = 0; j < 4; j++) acc[i][j] = MFMA16(bfr[j], af[i], acc[i][j]);
            } else {
#pragma unroll
                for (int i = 0; i < 4; i++)
#pragma unroll
                    for (int j = 0; j < 4; j++) acc[i][j] = MFMA16(af[i], bfr[j], acc[i][j]);
            }
        }
        __syncthreads();
    }

    if (z < 2) {
        // lane holds C[n = nBase+wn*64+j*16+qd*4+r][m = mBase+wm*64+i*16+ln]
        float qs = (z == 0) ? 0.18033688011111773f : 1.0f;  // (1/8)*log2(e)
#pragma unroll
        for (int j = 0; j < 4; j++) {
            int n0 = nBase + wn * 64 + j * 16 + qd * 4;
            float4 b4 = *(const float4*)&bias[n0];
            int h = n0 >> 6, dd = n0 & 63;
#pragma unroll
            for (int i = 0; i < 4; i++) {
                int m = mBase + wm * 64 + i * 16 + ln;
                int b = m >> 10, s = m & 1023;
                ushort4 o;
                o.x = f2bf((acc[i][j][0] + b4.x) * qs);
                o.y = f2bf((acc[i][j][1] + b4.y) * qs);
                o.z = f2bf((acc[i][j][2] + b4.z) * qs);
                o.w = f2bf((acc[i][j][3] + b4.w) * qs);
                *(ushort4*)&dst[((size_t)(b * H_ + h) * S_ + s) * D_ + dd] = o;
            }
        }
    } else {
        // lane holds C[m = mBase+wm*64+i*16+qd*4+r][n = nBase+wn*64+j*16+ln];
        // key-perm: sp = (s&~63)|(s&0x23)|((s&0x0C)<<1)|((s&0x10)>>2), r-bits
        // low -> 4 reg values consecutive in sp.
#pragma unroll
        for (int j = 0; j < 4; j++) {
            int n = nBase + wn * 64 + j * 16 + ln;
            float bb = bias[n];
            int h = n >> 6, dd = n & 63;
#pragma unroll
            for (int i = 0; i < 4; i++) {
                int s0 = mBase + wm * 64 + i * 16 + qd * 4;  // r=0; s0%4==0
                int b = s0 >> 10, s = s0 & 1023;
                int sp0 = (s & ~63) | (s & 0x23) | ((s & 0x0C) << 1) | ((s & 0x10) >> 2);
                ushort4 o;
                o.x = f2bf(acc[i][j][0] + bb);
                o.y = f2bf(acc[i][j][1] + bb);
                o.z = f2bf(acc[i][j][2] + bb);
                o.w = f2bf(acc[i][j][3] + bb);
                *(ushort4*)&dst[((size_t)(b * H_ + h) * D_ + dd) * S_ + sp0] = o;
            }
        }
    }
}

// Flash attention (R9/R11-exact). grid 1024 linear, block 256 (4 waves x 32
// queries), 4 blk/CU. XCD grouping: bh=((L&7)<<4)|((L>>3)&15), qx=L>>7 ->
// XCD c owns bh [16c,16c+16) (K/V 4MB = one L2).
// Q,K: [B,H,S,D] bf16 (Q pre-scaled by 0.125*log2e); V: [B,H,D,S] key-permuted.
// Swapped QK^T: sc[i][j][r] = P[key=j*16+qd*4+r][q=i*16+ln]; softmax+P->bf16
// in-register (pfrag = PV B-operand); V A-frags b128 from Vs (pre-permuted Vt).
__global__ __launch_bounds__(256, 4) void attn(const ushort_t* __restrict__ Qd,
                                               const ushort_t* __restrict__ Kd,
                                               const ushort_t* __restrict__ Vt,
                                               float* __restrict__ out) {
    __shared__ __attribute__((aligned(16))) ushort_t Ks[2][4096];   // [buf][64 keys x 64 d]
    __shared__ __attribute__((aligned(16))) ushort_t Vs[2][4096];   // [buf][64 d x 64 perm-keys]

    int L = blockIdx.x;
    int bh = ((L & 7) << 4) | ((L >> 3) & 15);
    int qx = L >> 7;
    int t = threadIdx.x, w = t >> 6, lane = t & 63;
    int ln = lane & 15, qd = lane >> 4;
    int qbase = qx * 128 + w * 32;
    const ushort_t* Qb = Qd + (size_t)bh * S_ * D_;
    const ushort_t* Kb = Kd + (size_t)bh * S_ * D_;
    const ushort_t* Vb = Vt + (size_t)bh * D_ * S_;

    // Q frags: lane ln holds row (q), qd*8 d-offset (B operand of swapped QK^T)
    bf16x8 qf[2][2];
#pragma unroll
    for (int i = 0; i < 2; i++) {
        const ushort_t* qp = Qb + (size_t)(qbase + i * 16 + ln) * D_ + qd * 8;
        qf[i][0] = *(const bf16x8*)qp;
        qf[i][1] = *(const bf16x8*)(qp + 32);
    }

    // staging per-lane constants (8 rows x 64 elem per 1KB async16 block)
    int l8 = lane >> 3, s8 = lane & 7;
    int stgOff = (s8 ^ l8) << 3;  // swizzled 8-elem segment
    const ushort_t* kg = Kb + (size_t)(w * 16 + l8) * D_ + stgOff;
    const ushort_t* vg = Vb + (size_t)(w * 16 + l8) * S_ + stgOff;
    // K frag-read: row ln (mod 16), seg qd swizzled by row&7
    int kOff = ln * 64 + ((qd ^ (ln & 7)) << 3);

    float rs[2] = {0.f, 0.f};
    f32x4 zero = {0.f, 0.f, 0.f, 0.f};
    f32x4 accO[2][4];
#pragma unroll
    for (int i = 0; i < 2; i++)
#pragma unroll
        for (int jd = 0; jd < 4; jd++) accO[i][jd] = zero;

    // preload chunk 0 into buf 0 (4 async16 per wave: 2 K-blocks + 2 V-blocks)
    async16(kg, &Ks[0][w * 1024]);
    async16(kg + 8 * D_, &Ks[0][w * 1024 + 512]);
    async16(vg, &Vs[0][w * 1024]);
    async16(vg + 8 * S_, &Vs[0][w * 1024 + 512]);

    for (int c = 0; c < 16; ++c) {
        int buf = c & 1;
        __builtin_amdgcn_s_waitcnt(0x0F70);  // vmcnt(0): chunk c staged
        __syncthreads();                     // all waves: staged + done reading buf^1
        if (c + 1 < 16) {                    // prefetch c+1; lands during compute(c)
            int kc = (c + 1) * 64;
            async16(kg + (size_t)kc * D_, &Ks[buf ^ 1][w * 1024]);
            async16(kg + (size_t)kc * D_ + 8 * D_, &Ks[buf ^ 1][w * 1024 + 512]);
            async16(vg + kc, &Vs[buf ^ 1][w * 1024]);
            async16(vg + kc + 8 * S_, &Vs[buf ^ 1][w * 1024 + 512]);
        }

        // S^T = K Q^T (swapped): sc[i][j][r] = P[key=j*16+qd*4+r][q=i*16+ln]
        f32x4 sc[2][4];
#pragma unroll
        for (int i = 0; i < 2; i++)
#pragma unroll
            for (int j = 0; j < 4; j++) sc[i][j] = zero;
        __builtin_amdgcn_s_setprio(1);
#pragma unroll
        for (int j = 0; j < 4; j++) {
            bf16x8 k0 = *(const bf16x8*)&Ks[buf][j * 1024 + kOff];
            bf16x8 k1 = *(const bf16x8*)&Ks[buf][(j * 1024 + kOff) ^ 32];
#pragma unroll
            for (int i = 0; i < 2; i++) {
                sc[i][j] = MFMA16(k0, qf[i][0], sc[i][j]);
                sc[i][j] = MFMA16(k1, qf[i][1], sc[i][j]);
            }
        }
        __builtin_amdgcn_s_setprio(0);

        // softmax + P^T B-frags in-register: pfrag[i][m] element e holds
        // bf16(exp2(sc[i][2m+(e>>2)][e&3])) = P[key 32m+16jh+4qd+r][q]
        bf16x8 pfrag[2][2];
#pragma unroll
        for (int i = 0; i < 2; i++)
#pragma unroll
            for (int m = 0; m < 2; m++) {
                union { unsigned u[4]; bf16x8 v; } pk;
#pragma unroll
                for (int jh = 0; jh < 2; jh++) {
                    float p0 = exp2f(sc[i][2 * m + jh][0]);
                    float p1 = exp2f(sc[i][2 * m + jh][1]);
                    float p2 = exp2f(sc[i][2 * m + jh][2]);
                    float p3 = exp2f(sc[i][2 * m + jh][3]);
                    rs[i] += (p0 + p1) + (p2 + p3);
                    pk.u[jh * 2]     = f2bf_rhu_u(p0) | (f2bf_rhu_u(p1) << 16);
                    pk.u[jh * 2 + 1] = f2bf_rhu_u(p2) | (f2bf_rhu_u(p3) << 16);
                }
                pfrag[i][m] = pk.v;
            }

        // O^T += V^T P^T (V A-frags: row d=dt*16+ln, perm-key seg (4m+qd)^(d&7))
        __builtin_amdgcn_s_setprio(1);
#pragma unroll
        for (int dt = 0; dt < 4; dt++)
#pragma unroll
            for (int m = 0; m < 2; m++) {
                bf16x8 vf = *(const bf16x8*)&Vs[buf][(dt * 16 + ln) * 64 +
                                                    ((((m << 2) + qd) ^ (ln & 7)) << 3)];
                accO[0][dt] = MFMA16(vf, pfrag[0][m], accO[0][dt]);
                accO[1][dt] = MFMA16(vf, pfrag[1][m], accO[1][dt]);
            }
        __builtin_amdgcn_s_setprio(0);
    }

    // denominators: rs[i] = this lane's partial for q=i*16+ln (16 keys/chunk);
    // full sum over the 4 qd lanes (xor bits 4,5). inv valid on every lane.
    float inv[2];
#pragma unroll
    for (int i = 0; i < 2; i++) {
        float s = rs[i];
        s += __shfl_xor(s, 16);
        s += __shfl_xor(s, 32);
        inv[i] = 1.f / s;
    }
    int b = bh >> 4, h = bh & 15;
#pragma unroll
    for (int i = 0; i < 2; i++) {
        int q = qbase + i * 16 + ln;
        float* op = out + ((size_t)(b * S_ + q) * H_ + h) * D_ + qd * 4;
#pragma unroll
        for (int dt = 0; dt < 4; dt++) {
            float4 o4;
            o4.x = accO[i][dt][0] * inv[i];
            o4.y = accO[i][dt][1] * inv[i];
            o4.z = accO[i][dt][2] * inv[i];
            o4.w = accO[i][dt][3] * inv[i];
            *(float4*)(op + dt * 16) = o4;
        }
    }
}

extern "C" void kernel_launch(void* const* d_in, const int* in_sizes, int n_in,
                              void* d_out, int out_size, void* d_ws, size_t ws_size,
                              hipStream_t stream) {
    const float* from = (const float*)d_in[0];
    const float* to_  = (const float*)d_in[1];
    const float* Wq = (const float*)d_in[2];
    const float* bq = (const float*)d_in[3];
    const float* Wk = (const float*)d_in[4];
    const float* bk = (const float*)d_in[5];
    const float* Wv = (const float*)d_in[6];
    const float* bv = (const float*)d_in[7];
    float* out = (float*)d_out;

    const size_t NTOK = (size_t)B_ * S_ * W_;  // 8388608
    ushort_t* ws = (ushort_t*)d_ws;
    ushort_t* fromB = ws;
    ushort_t* toB = fromB + NTOK;
    ushort_t* Wt = toB + NTOK;
    ushort_t* Qd = Wt + (size_t)3 * W_ * W_;
    ushort_t* Kd = Qd + NTOK;
    ushort_t* Vt = Kd + NTOK;

    int n4 = (int)(NTOK / 4);
    prep<<<dim3(n4 / 256, 3), dim3(256), 0, stream>>>(from, to_, Wq, Wk, Wv, fromB, toB, Wt, n4);
    qkv_gemm<<<dim3(512, 3), dim3(256), 0, stream>>>(fromB, toB, Wt, bq, bk, bv, Qd, Kd, Vt);
    attn<<<dim3(1024), dim3(256), 0, stream>>>(Qd, Kd, Vt, out);
}